// Round 3
// baseline (262.325 us; speedup 1.0000x reference)
//
#include <hip/hip_runtime.h>
#include <hip/hip_bf16.h>
#include <string.h>

#define B_ 8
#define N_ 50000
#define F_ 32
#define S_ 16
#define O_ 64
#define K_ (F_ * S_)            // 512
#define NTILES ((B_ * N_) / 16) // 25000 16-vertex tiles (N % 16 == 0)
#define XELEMS (B_ * N_ * F_)   // 12.8M

typedef __attribute__((ext_vector_type(8))) short bf16x8;
typedef __attribute__((ext_vector_type(4))) float f32x4;

union bfpack { bf16x8 v; __hip_bfloat16 h[8]; };

// ---- Prepass: W -> bf16 fragment-swizzled (64 KB) + x -> bf16 rows (25.6 MB) ----
// Wb[((kt*4 + quad)*64 + o)*8 + j] = bf16(W[o*512 + kt*32 + quad*8 + j])
__global__ __launch_bounds__(256) void prep_kernel(const float* __restrict__ W,
                                                   unsigned short* __restrict__ Wb,
                                                   const float* __restrict__ x,
                                                   unsigned short* __restrict__ xb) {
    int bid = blockIdx.x;
    if (bid < 128) {
        int i = bid * 256 + threadIdx.x; // [0, 32768)
        int j = i & 7;
        int o = (i >> 3) & 63;
        int qk = i >> 9;
        int quad = qk & 3;
        int kt = qk >> 2;
        __hip_bfloat16 h = __float2bfloat16(W[o * K_ + kt * 32 + quad * 8 + j]);
        unsigned short u; memcpy(&u, &h, 2);
        Wb[i] = u;
    } else {
        int i = (bid - 128) * 256 + threadIdx.x; // [0, 1.6M) groups of 8
        if (i < XELEMS / 8) {
            size_t base = (size_t)i * 8;
            f32x4 a = __builtin_nontemporal_load((const f32x4*)(x + base));
            f32x4 b = __builtin_nontemporal_load((const f32x4*)(x + base + 4));
            bfpack p;
            p.h[0] = __float2bfloat16(a[0]); p.h[1] = __float2bfloat16(a[1]);
            p.h[2] = __float2bfloat16(a[2]); p.h[3] = __float2bfloat16(a[3]);
            p.h[4] = __float2bfloat16(b[0]); p.h[5] = __float2bfloat16(b[1]);
            p.h[6] = __float2bfloat16(b[2]); p.h[7] = __float2bfloat16(b[3]);
            *(bf16x8*)(xb + base) = p.v;
        }
    }
}

// ---- Main kernel: bf16 gathered GEMM, batched-MLP version ----
__global__ __launch_bounds__(256) void spiral_kernel(
        const unsigned short* __restrict__ xb, const int* __restrict__ adj,
        const unsigned short* __restrict__ Wb, const float* __restrict__ bias,
        float* __restrict__ out) {
    const int lane = threadIdx.x & 63;
    const int wv   = threadIdx.x >> 6;
    const int m16  = lane & 15;
    const int quad = lane >> 4;

    const int tile0 = (blockIdx.x * 4 + wv) * 4;

    int rowbase[4]; // b*N + n0
    int nn[4], bb[4];
#pragma unroll
    for (int vt = 0; vt < 4; ++vt) {
        int t = tile0 + vt;
        if (t >= NTILES) t = NTILES - 1; // clamp: duplicate identical stores, benign
        int g = t * 16;
        int bi = g / N_;
        bb[vt] = bi;
        nn[vt] = g - bi * N_;
        rowbase[vt] = g;
    }

    f32x4 acc[4][4];
#pragma unroll
    for (int vt = 0; vt < 4; ++vt)
#pragma unroll
        for (int nt = 0; nt < 4; ++nt)
            acc[vt][nt] = (f32x4){0.f, 0.f, 0.f, 0.f};

    // Prefetch adj for group 0
    int4 aj[4];
#pragma unroll
    for (int vt = 0; vt < 4; ++vt)
        aj[vt] = *(const int4*)(adj + (size_t)(rowbase[vt] + m16) * S_);

#pragma unroll
    for (int kt4 = 0; kt4 < 4; ++kt4) {
        // Issue ALL 16 gathers of this group up front (max MLP per wave).
        bf16x8 xf[4][4]; // [q][vt]
#pragma unroll
        for (int q = 0; q < 4; ++q)
#pragma unroll
            for (int vt = 0; vt < 4; ++vt) {
                int a = ((const int*)&aj[vt])[q];
                xf[q][vt] = *(const bf16x8*)(xb + (size_t)(bb[vt] * N_ + a) * F_ + quad * 8);
            }

        // Prefetch next group's adj behind the compute section.
        int4 ajn[4];
        if (kt4 < 3) {
#pragma unroll
            for (int vt = 0; vt < 4; ++vt)
                ajn[vt] = *(const int4*)(adj + (size_t)(rowbase[vt] + m16) * S_ + (kt4 + 1) * 4);
        }

        // Compute: 64 MFMAs while next adj (and tail gathers) are in flight.
#pragma unroll
        for (int q = 0; q < 4; ++q) {
            const int kt = kt4 * 4 + q;
            bf16x8 wf[4];
#pragma unroll
            for (int nt = 0; nt < 4; ++nt)
                wf[nt] = *(const bf16x8*)(Wb + (size_t)((kt * 4 + quad) * 64 + nt * 16 + m16) * 8);
#pragma unroll
            for (int vt = 0; vt < 4; ++vt)
#pragma unroll
                for (int nt = 0; nt < 4; ++nt)
                    // A = W-tile (m = o_local), B = x-tile (n = vertex)
                    acc[vt][nt] = __builtin_amdgcn_mfma_f32_16x16x32_bf16(wf[nt], xf[q][vt], acc[vt][nt], 0, 0, 0);
        }

        if (kt4 < 3) {
#pragma unroll
            for (int vt = 0; vt < 4; ++vt)
                aj[vt] = ajn[vt];
        }
    }

    // Epilogue. D layout: col = lane&15 = vertex, row = quad*4 + r = o within nt-tile.
    // Lane holds 4 consecutive o's for one vertex -> float4 nontemporal stores.
#pragma unroll
    for (int vt = 0; vt < 4; ++vt) {
        const int n = nn[vt] + m16;
        const bool zero = (n == N_ - 1);
        float* orow = out + (size_t)(rowbase[vt] + m16) * O_ + quad * 4;
#pragma unroll
        for (int nt = 0; nt < 4; ++nt) {
            f32x4 bv = *(const f32x4*)(bias + nt * 16 + quad * 4);
            f32x4 v;
#pragma unroll
            for (int r = 0; r < 4; ++r) {
                float t = acc[vt][nt][r] + bv[r];
                t = t > 0.f ? t : (__expf(t) - 1.f); // ELU alpha=1
                v[r] = zero ? 0.f : t;
            }
            __builtin_nontemporal_store(v, (f32x4*)(orow + nt * 16));
        }
    }
}

// ---- Fallback (ws too small): fp32-gather kernel ----
__global__ __launch_bounds__(256) void wconv_kernel(const float* __restrict__ W,
                                                    unsigned short* __restrict__ Wb) {
    int i = blockIdx.x * 256 + threadIdx.x;
    if (i < O_ * K_) {
        int j = i & 7, o = (i >> 3) & 63, qk = i >> 9;
        int quad = qk & 3, kt = qk >> 2;
        __hip_bfloat16 h = __float2bfloat16(W[o * K_ + kt * 32 + quad * 8 + j]);
        unsigned short u; memcpy(&u, &h, 2);
        Wb[i] = u;
    }
}

__global__ __launch_bounds__(256) void spiral_f32_kernel(
        const float* __restrict__ x, const int* __restrict__ adj,
        const unsigned short* __restrict__ Wb, const float* __restrict__ bias,
        float* __restrict__ out) {
    const int lane = threadIdx.x & 63;
    const int wv = threadIdx.x >> 6;
    const int m16 = lane & 15, quad = lane >> 4;
    const int tile0 = (blockIdx.x * 4 + wv) * 4;
    int bb[4], nn[4];
#pragma unroll
    for (int vt = 0; vt < 4; ++vt) {
        int t = tile0 + vt;
        if (t >= NTILES) t = NTILES - 1;
        int g = t * 16, bi = g / N_;
        bb[vt] = bi; nn[vt] = g - bi * N_;
    }
    f32x4 acc[4][4];
#pragma unroll
    for (int vt = 0; vt < 4; ++vt)
#pragma unroll
        for (int nt = 0; nt < 4; ++nt) acc[vt][nt] = (f32x4){0.f,0.f,0.f,0.f};
    for (int kt = 0; kt < 16; ++kt) {
        bf16x8 wf[4];
#pragma unroll
        for (int nt = 0; nt < 4; ++nt)
            wf[nt] = *(const bf16x8*)(Wb + (size_t)((kt * 4 + quad) * 64 + nt * 16 + m16) * 8);
#pragma unroll
        for (int vt = 0; vt < 4; ++vt) {
            int n = nn[vt] + m16;
            int a = adj[(size_t)(bb[vt] * N_ + n) * S_ + kt];
            const float* xr = x + (size_t)(bb[vt] * N_ + a) * F_ + quad * 8;
            f32x4 x0 = *(const f32x4*)xr;
            f32x4 x1 = *(const f32x4*)(xr + 4);
            bfpack af;
            af.h[0]=__float2bfloat16(x0[0]); af.h[1]=__float2bfloat16(x0[1]);
            af.h[2]=__float2bfloat16(x0[2]); af.h[3]=__float2bfloat16(x0[3]);
            af.h[4]=__float2bfloat16(x1[0]); af.h[5]=__float2bfloat16(x1[1]);
            af.h[6]=__float2bfloat16(x1[2]); af.h[7]=__float2bfloat16(x1[3]);
#pragma unroll
            for (int nt = 0; nt < 4; ++nt)
                acc[vt][nt] = __builtin_amdgcn_mfma_f32_16x16x32_bf16(wf[nt], af.v, acc[vt][nt], 0, 0, 0);
        }
    }
#pragma unroll
    for (int vt = 0; vt < 4; ++vt) {
        const int n = nn[vt] + m16;
        const bool zero = (n == N_ - 1);
        float* orow = out + (size_t)(bb[vt] * N_ + n) * O_ + quad * 4;
#pragma unroll
        for (int nt = 0; nt < 4; ++nt) {
            f32x4 bv = *(const f32x4*)(bias + nt * 16 + quad * 4);
            f32x4 v;
#pragma unroll
            for (int r = 0; r < 4; ++r) {
                float t = acc[vt][nt][r] + bv[r];
                t = t > 0.f ? t : (__expf(t) - 1.f);
                v[r] = zero ? 0.f : t;
            }
            *(f32x4*)(orow + nt * 16) = v;
        }
    }
}

extern "C" void kernel_launch(void* const* d_in, const int* in_sizes, int n_in,
                              void* d_out, int out_size, void* d_ws, size_t ws_size,
                              hipStream_t stream) {
    const float* x    = (const float*)d_in[0];
    const int*   adj  = (const int*)d_in[1];
    const float* W    = (const float*)d_in[2];
    const float* bias = (const float*)d_in[3];
    float* out = (float*)d_out;

    const size_t wb_bytes = (size_t)O_ * K_ * 2;            // 64 KB
    const size_t xb_bytes = (size_t)XELEMS * 2;             // 25.6 MB
    unsigned short* Wb = (unsigned short*)d_ws;
    unsigned short* xb = (unsigned short*)((char*)d_ws + wb_bytes);

    const int grid_main = (NTILES + 15) / 16; // 1563

    if (ws_size >= wb_bytes + xb_bytes) {
        int grid_prep = 128 + (XELEMS / 8 + 255) / 256; // 128 + 6250
        hipLaunchKernelGGL(prep_kernel, dim3(grid_prep), dim3(256), 0, stream, W, Wb, x, xb);
        hipLaunchKernelGGL(spiral_kernel, dim3(grid_main), dim3(256), 0, stream,
                           xb, adj, Wb, bias, out);
    } else {
        hipLaunchKernelGGL(wconv_kernel, dim3(128), dim3(256), 0, stream, W, Wb);
        hipLaunchKernelGGL(spiral_f32_kernel, dim3(grid_main), dim3(256), 0, stream,
                           x, adj, Wb, bias, out);
    }
}

// Round 4
// 237.145 us; speedup vs baseline: 1.1062x; 1.1062x over previous
//
#include <hip/hip_runtime.h>
#include <hip/hip_bf16.h>
#include <string.h>

#define B_ 8
#define N_ 50000
#define F_ 32
#define S_ 16
#define O_ 64
#define K_ (F_ * S_)            // 512
#define XELEMS (B_ * N_ * F_)   // 12.8M
#define TPB (N_ / 16)           // 3125 tiles per batch
#define BPB 196                 // blocks per batch (196*16 = 3136 >= 3125)

typedef __attribute__((ext_vector_type(8))) short bf16x8;
typedef __attribute__((ext_vector_type(4))) float f32x4;

union bfpack { bf16x8 v; __hip_bfloat16 h[8]; };

// ---- Prepass: W -> bf16 fragment-swizzled (64 KB) + x -> bf16 rows (25.6 MB) ----
// Wb[((kt*4 + quad)*64 + o)*8 + j] = bf16(W[o*512 + kt*32 + quad*8 + j])
__global__ __launch_bounds__(256) void prep_kernel(const float* __restrict__ W,
                                                   unsigned short* __restrict__ Wb,
                                                   const float* __restrict__ x,
                                                   unsigned short* __restrict__ xb) {
    int bid = blockIdx.x;
    if (bid < 128) {
        int i = bid * 256 + threadIdx.x; // [0, 32768)
        int j = i & 7;
        int o = (i >> 3) & 63;
        int qk = i >> 9;
        int quad = qk & 3;
        int kt = qk >> 2;
        __hip_bfloat16 h = __float2bfloat16(W[o * K_ + kt * 32 + quad * 8 + j]);
        unsigned short u; memcpy(&u, &h, 2);
        Wb[i] = u;
    } else {
        int i = (bid - 128) * 256 + threadIdx.x; // [0, 1.6M) groups of 8
        if (i < XELEMS / 8) {
            size_t base = (size_t)i * 8;
            f32x4 a = __builtin_nontemporal_load((const f32x4*)(x + base));
            f32x4 b = __builtin_nontemporal_load((const f32x4*)(x + base + 4));
            bfpack p;
            p.h[0] = __float2bfloat16(a[0]); p.h[1] = __float2bfloat16(a[1]);
            p.h[2] = __float2bfloat16(a[2]); p.h[3] = __float2bfloat16(a[3]);
            p.h[4] = __float2bfloat16(b[0]); p.h[5] = __float2bfloat16(b[1]);
            p.h[6] = __float2bfloat16(b[2]); p.h[7] = __float2bfloat16(b[3]);
            *(bf16x8*)(xb + base) = p.v;
        }
    }
}

// ---- Main kernel: bf16 gathered GEMM, batch<->XCD partitioned ----
// Block i works ONLY on batch (i & 7). Blocks round-robin to XCDs (i % 8),
// so each XCD's L2 sees a single 6.4 MB batch slice instead of all 25.6 MB.
__global__ __launch_bounds__(256) void spiral_kernel(
        const unsigned short* __restrict__ xb, const int* __restrict__ adj,
        const unsigned short* __restrict__ Wb, const float* __restrict__ bias,
        float* __restrict__ out) {
    const int lane = threadIdx.x & 63;
    const int wv   = threadIdx.x >> 6;
    const int m16  = lane & 15;
    const int quad = lane >> 4;

    const int b  = blockIdx.x & 7;   // batch == intended XCD
    const int jb = blockIdx.x >> 3;  // 0..195 block-within-batch
    const int tib0 = (jb * 4 + wv) * 4;

    int rowbase[4]; // b*N + n0 (n0 = tile start vertex within batch)
    int nn[4];
#pragma unroll
    for (int vt = 0; vt < 4; ++vt) {
        int t = tib0 + vt;
        if (t >= TPB) t = TPB - 1; // clamp within batch: duplicate identical stores, benign
        nn[vt] = t * 16;
        rowbase[vt] = b * N_ + t * 16;
    }
    const size_t xbase = (size_t)b * N_ * F_;

    f32x4 acc[4][4];
#pragma unroll
    for (int vt = 0; vt < 4; ++vt)
#pragma unroll
        for (int nt = 0; nt < 4; ++nt)
            acc[vt][nt] = (f32x4){0.f, 0.f, 0.f, 0.f};

#pragma unroll
    for (int kt4 = 0; kt4 < 4; ++kt4) {
        // adj rows: lane's vertex row = rowbase+m16; 4 kt's of neighbor ids at once
        int4 aj[4];
#pragma unroll
        for (int vt = 0; vt < 4; ++vt)
            aj[vt] = *(const int4*)(adj + (size_t)(rowbase[vt] + m16) * S_ + kt4 * 4);

#pragma unroll
        for (int q = 0; q < 4; ++q) {
            const int kt = kt4 * 4 + q;
            bf16x8 xf[4];
#pragma unroll
            for (int vt = 0; vt < 4; ++vt) {
                int a = ((const int*)&aj[vt])[q];
                xf[vt] = *(const bf16x8*)(xb + xbase + (size_t)a * F_ + quad * 8);
            }
            bf16x8 wf[4];
#pragma unroll
            for (int nt = 0; nt < 4; ++nt)
                wf[nt] = *(const bf16x8*)(Wb + (size_t)((kt * 4 + quad) * 64 + nt * 16 + m16) * 8);
#pragma unroll
            for (int vt = 0; vt < 4; ++vt)
#pragma unroll
                for (int nt = 0; nt < 4; ++nt)
                    // A = W-tile (m = o_local), B = x-tile (n = vertex)
                    acc[vt][nt] = __builtin_amdgcn_mfma_f32_16x16x32_bf16(wf[nt], xf[vt], acc[vt][nt], 0, 0, 0);
        }
    }

    // Epilogue. D layout: col = lane&15 = vertex, row = quad*4 + r = o within nt-tile.
    // Lane holds 4 consecutive o's for one vertex -> float4 stores.
#pragma unroll
    for (int vt = 0; vt < 4; ++vt) {
        const int n = nn[vt] + m16;
        const bool zero = (n == N_ - 1);
        float* orow = out + (size_t)(rowbase[vt] + m16) * O_ + quad * 4;
#pragma unroll
        for (int nt = 0; nt < 4; ++nt) {
            f32x4 bv = *(const f32x4*)(bias + nt * 16 + quad * 4);
            f32x4 v;
#pragma unroll
            for (int r = 0; r < 4; ++r) {
                float t = acc[vt][nt][r] + bv[r];
                t = t > 0.f ? t : (__expf(t) - 1.f); // ELU alpha=1
                v[r] = zero ? 0.f : t;
            }
            *(f32x4*)(orow + nt * 16) = v;
        }
    }
}

// ---- Fallback (ws too small): fp32-gather kernel ----
__global__ __launch_bounds__(256) void wconv_kernel(const float* __restrict__ W,
                                                    unsigned short* __restrict__ Wb) {
    int i = blockIdx.x * 256 + threadIdx.x;
    if (i < O_ * K_) {
        int j = i & 7, o = (i >> 3) & 63, qk = i >> 9;
        int quad = qk & 3, kt = qk >> 2;
        __hip_bfloat16 h = __float2bfloat16(W[o * K_ + kt * 32 + quad * 8 + j]);
        unsigned short u; memcpy(&u, &h, 2);
        Wb[i] = u;
    }
}

__global__ __launch_bounds__(256) void spiral_f32_kernel(
        const float* __restrict__ x, const int* __restrict__ adj,
        const unsigned short* __restrict__ Wb, const float* __restrict__ bias,
        float* __restrict__ out) {
    const int lane = threadIdx.x & 63;
    const int wv = threadIdx.x >> 6;
    const int m16 = lane & 15, quad = lane >> 4;
    const int b  = blockIdx.x & 7;
    const int jb = blockIdx.x >> 3;
    const int tib0 = (jb * 4 + wv) * 4;
    int rowbase[4], nn[4];
#pragma unroll
    for (int vt = 0; vt < 4; ++vt) {
        int t = tib0 + vt;
        if (t >= TPB) t = TPB - 1;
        nn[vt] = t * 16;
        rowbase[vt] = b * N_ + t * 16;
    }
    f32x4 acc[4][4];
#pragma unroll
    for (int vt = 0; vt < 4; ++vt)
#pragma unroll
        for (int nt = 0; nt < 4; ++nt) acc[vt][nt] = (f32x4){0.f,0.f,0.f,0.f};
    for (int kt = 0; kt < 16; ++kt) {
        bf16x8 wf[4];
#pragma unroll
        for (int nt = 0; nt < 4; ++nt)
            wf[nt] = *(const bf16x8*)(Wb + (size_t)((kt * 4 + quad) * 64 + nt * 16 + m16) * 8);
#pragma unroll
        for (int vt = 0; vt < 4; ++vt) {
            int a = adj[(size_t)(rowbase[vt] + m16) * S_ + kt];
            const float* xr = x + ((size_t)b * N_ + a) * F_ + quad * 8;
            f32x4 x0 = *(const f32x4*)xr;
            f32x4 x1 = *(const f32x4*)(xr + 4);
            bfpack af;
            af.h[0]=__float2bfloat16(x0[0]); af.h[1]=__float2bfloat16(x0[1]);
            af.h[2]=__float2bfloat16(x0[2]); af.h[3]=__float2bfloat16(x0[3]);
            af.h[4]=__float2bfloat16(x1[0]); af.h[5]=__float2bfloat16(x1[1]);
            af.h[6]=__float2bfloat16(x1[2]); af.h[7]=__float2bfloat16(x1[3]);
#pragma unroll
            for (int nt = 0; nt < 4; ++nt)
                acc[vt][nt] = __builtin_amdgcn_mfma_f32_16x16x32_bf16(wf[nt], af.v, acc[vt][nt], 0, 0, 0);
        }
    }
#pragma unroll
    for (int vt = 0; vt < 4; ++vt) {
        const int n = nn[vt] + m16;
        const bool zero = (n == N_ - 1);
        float* orow = out + (size_t)(rowbase[vt] + m16) * O_ + quad * 4;
#pragma unroll
        for (int nt = 0; nt < 4; ++nt) {
            f32x4 bv = *(const f32x4*)(bias + nt * 16 + quad * 4);
            f32x4 v;
#pragma unroll
            for (int r = 0; r < 4; ++r) {
                float t = acc[vt][nt][r] + bv[r];
                t = t > 0.f ? t : (__expf(t) - 1.f);
                v[r] = zero ? 0.f : t;
            }
            *(f32x4*)(orow + nt * 16) = v;
        }
    }
}

extern "C" void kernel_launch(void* const* d_in, const int* in_sizes, int n_in,
                              void* d_out, int out_size, void* d_ws, size_t ws_size,
                              hipStream_t stream) {
    const float* x    = (const float*)d_in[0];
    const int*   adj  = (const int*)d_in[1];
    const float* W    = (const float*)d_in[2];
    const float* bias = (const float*)d_in[3];
    float* out = (float*)d_out;

    const size_t wb_bytes = (size_t)O_ * K_ * 2;            // 64 KB
    const size_t xb_bytes = (size_t)XELEMS * 2;             // 25.6 MB
    unsigned short* Wb = (unsigned short*)d_ws;
    unsigned short* xb = (unsigned short*)((char*)d_ws + wb_bytes);

    const int grid_main = 8 * BPB; // 1568 blocks, batch = blockIdx % 8

    if (ws_size >= wb_bytes + xb_bytes) {
        int grid_prep = 128 + (XELEMS / 8 + 255) / 256; // 128 + 6250
        hipLaunchKernelGGL(prep_kernel, dim3(grid_prep), dim3(256), 0, stream, W, Wb, x, xb);
        hipLaunchKernelGGL(spiral_kernel, dim3(grid_main), dim3(256), 0, stream,
                           xb, adj, Wb, bias, out);
    } else {
        hipLaunchKernelGGL(wconv_kernel, dim3(128), dim3(256), 0, stream, W, Wb);
        hipLaunchKernelGGL(spiral_f32_kernel, dim3(grid_main), dim3(256), 0, stream,
                           x, adj, Wb, bias, out);
    }
}